// Round 8
// baseline (937.270 us; speedup 1.0000x reference)
//
#include <hip/hip_runtime.h>
#include <hip/hip_bf16.h>
#include <hip/hip_fp16.h>

#define D 16
#define RNODES 128            // nodes per bucket (tgt>>7)
#define SCAN_B 512

typedef _Float16 f16x4 __attribute__((ext_vector_type(4)));
typedef float f32x4 __attribute__((ext_vector_type(4)));

// ---------------- Kernel A: q,v per node (packed [n][32] f16: q | v) ----------------
__global__ void node_prep_qv(const float* __restrict__ x,
                             const float* __restrict__ Wq, const float* __restrict__ bq,
                             const float* __restrict__ Wv, const float* __restrict__ bv,
                             __half* __restrict__ qv_h, int n_nodes) {
    __shared__ float sWq[D * D], sWv[D * D], sb[2 * D];
    for (int i = threadIdx.x; i < D * D; i += blockDim.x) { sWq[i] = Wq[i]; sWv[i] = Wv[i]; }
    if (threadIdx.x < D) { sb[threadIdx.x] = bq[threadIdx.x]; sb[D + threadIdx.x] = bv[threadIdx.x]; }
    __syncthreads();
    int n = blockIdx.x * blockDim.x + threadIdx.x;
    if (n >= n_nodes) return;
    float xr[D];
    const float4* xp = (const float4*)(x + (size_t)n * D);
#pragma unroll
    for (int i = 0; i < 4; i++) {
        float4 t = xp[i];
        xr[4*i] = t.x; xr[4*i+1] = t.y; xr[4*i+2] = t.z; xr[4*i+3] = t.w;
    }
    float qr[D], vr[D];
#pragma unroll
    for (int c = 0; c < D; c++) { qr[c] = sb[c]; vr[c] = sb[D + c]; }
#pragma unroll
    for (int j = 0; j < D; j++) {
        float xj = xr[j];
#pragma unroll
        for (int c = 0; c < D; c++) {
            qr[c] = fmaf(xj, sWq[j * D + c], qr[c]);
            vr[c] = fmaf(xj, sWv[j * D + c], vr[c]);
        }
    }
    __align__(16) __half2 qp[16];
#pragma unroll
    for (int i = 0; i < 8; i++) qp[i]     = __floats2half2_rn(qr[2*i], qr[2*i+1]);
#pragma unroll
    for (int i = 0; i < 8; i++) qp[8 + i] = __floats2half2_rn(vr[2*i], vr[2*i+1]);
    float4* qd = (float4*)(qv_h + (size_t)n * 32);
#pragma unroll
    for (int i = 0; i < 4; i++) qd[i] = *(float4*)&qp[4*i];
}

// ---------------- hist: per-bucket edge counts (LDS histogram) ----------------
__global__ void hist_bucket(const int* __restrict__ ei, int* __restrict__ counts,
                            int n_edges, int nb) {
    __shared__ int lh[4096];
    if (nb <= 4096) {
        for (int j = threadIdx.x; j < nb; j += blockDim.x) lh[j] = 0;
        __syncthreads();
        size_t stride = (size_t)gridDim.x * blockDim.x;
        for (size_t e = (size_t)blockIdx.x * blockDim.x + threadIdx.x; e < (size_t)n_edges; e += stride) {
            int tgt = __builtin_nontemporal_load(&ei[(size_t)n_edges + e]);
            atomicAdd(&lh[tgt >> 7], 1);
        }
        __syncthreads();
        for (int j = threadIdx.x; j < nb; j += blockDim.x)
            if (lh[j]) atomicAdd(&counts[j], lh[j]);
    } else {
        size_t stride = (size_t)gridDim.x * blockDim.x;
        for (size_t e = (size_t)blockIdx.x * blockDim.x + threadIdx.x; e < (size_t)n_edges; e += stride) {
            int tgt = ei[(size_t)n_edges + e];
            atomicAdd(&counts[tgt >> 7], 1);
        }
    }
}

// ---------------- scan (R3-proven 3-kernel exclusive scan) ----------------
__global__ void scan1(const int* __restrict__ counts, int* __restrict__ rowptr,
                      int* __restrict__ bsum, int n) {
    __shared__ int tmp[SCAN_B];
    int i = blockIdx.x * SCAN_B + threadIdx.x;
    int v = (i < n) ? counts[i] : 0;
    tmp[threadIdx.x] = v;
    __syncthreads();
    for (int off = 1; off < SCAN_B; off <<= 1) {
        int t = (threadIdx.x >= off) ? tmp[threadIdx.x - off] : 0;
        __syncthreads();
        tmp[threadIdx.x] += t;
        __syncthreads();
    }
    if (i < n) rowptr[i] = tmp[threadIdx.x] - v;  // exclusive
    if (threadIdx.x == SCAN_B - 1) bsum[blockIdx.x] = tmp[threadIdx.x];
}

__global__ void scan2(int* __restrict__ bsum, int nb) {
    __shared__ int tmp[1024];
    int v = (threadIdx.x < nb) ? bsum[threadIdx.x] : 0;
    tmp[threadIdx.x] = v;
    __syncthreads();
    for (int off = 1; off < 1024; off <<= 1) {
        int t = (threadIdx.x >= off) ? tmp[threadIdx.x - off] : 0;
        __syncthreads();
        tmp[threadIdx.x] += t;
        __syncthreads();
    }
    if (threadIdx.x < nb) bsum[threadIdx.x] = tmp[threadIdx.x] - v;  // exclusive
}

__global__ void scan3(int* __restrict__ rowptr, int* __restrict__ cursor,
                      const int* __restrict__ bsum, int n) {
    int i = blockIdx.x * blockDim.x + threadIdx.x;
    if (i >= n) return;
    int r = rowptr[i] + bsum[i / SCAN_B];
    rowptr[i] = r;
    cursor[i] = r;
}

// ---------------- scatter: bucket-sorted 8B records {src|tgtlo<<19, eidx} ----------------
__global__ void scatter_pack(const int* __restrict__ ei, int* __restrict__ cursor,
                             uint2* __restrict__ rec, int n_edges) {
    int e = blockIdx.x * blockDim.x + threadIdx.x;
    if (e >= n_edges) return;
    int src = __builtin_nontemporal_load(&ei[e]);
    int tgt = __builtin_nontemporal_load(&ei[(size_t)n_edges + e]);
    int b = tgt >> 7;
    unsigned lo = (unsigned)(tgt & (RNODES - 1));
    int pos = atomicAdd(&cursor[b], 1);
    rec[pos] = make_uint2((unsigned)src | (lo << 19), (unsigned)e);
}

// ---------------- accum: one block per bucket; LDS accumulation, NO fabric atomics ----
// Per bucket: compute k & skip for its 128 nodes from x; loop edges (16/wave) with
// MFMA for e = ea@We (R6-proven fragment layout); LDS f32 atomicAdd into hagg;
// write h = hagg + skip once, coalesced; fused BN partial sums.
__global__ void accum_bucket(const float* __restrict__ x,
                             const float* __restrict__ ea,
                             const uint2* __restrict__ rec,
                             const int* __restrict__ rowptr,
                             const int* __restrict__ counts,
                             const float* __restrict__ We,
                             const float* __restrict__ Wk, const float* __restrict__ bk,
                             const float* __restrict__ Ws, const float* __restrict__ bs,
                             const float* __restrict__ bias,
                             const __half* __restrict__ qv_h,
                             float* __restrict__ h, float* __restrict__ stats,
                             int n_nodes, int n_edges) {
    __shared__ float hagg[RNODES * D];
    __shared__ float kls[RNODES * D];
    __shared__ float sls[RNODES * D];
    __shared__ float red[2][4 * D];

    int t = threadIdx.x;
    int b = blockIdx.x;
    int c = t & 15;
    int lane = t & 63;
    int wv = t >> 6;            // wave 0..3
    int g = lane >> 4;          // group in wave 0..3
    int seg = t >> 4;           // 16-lane segment 0..15
    int base_node = b * RNODES;

    for (int i = t; i < RNODES * D; i += 256) hagg[i] = 0.f;

    // k & skip for this bucket's nodes (16 lanes per node, 8 passes)
#pragma unroll
    for (int p = 0; p < 8; ++p) {
        int nlo = seg + 16 * p;
        int node = base_node + nlo;
        float kk = bk[c];
        float sk = bs[c] + bias[c];
        if (node < n_nodes) {
            float xc = x[(size_t)node * D + c];
#pragma unroll
            for (int j = 0; j < D; ++j) {
                float xj = __shfl(xc, j, D);
                kk = fmaf(xj, Wk[j * D + c], kk);
                sk = fmaf(xj, Ws[j * D + c], sk);
            }
        }
        kls[nlo * D + c] = kk;
        sls[nlo * D + c] = sk;
    }
    __syncthreads();

    // B fragment: We[k][c], k = 4*g + i
    f16x4 bfrag;
#pragma unroll
    for (int i = 0; i < 4; i++) bfrag[i] = (_Float16)We[(4 * g + i) * D + c];

    int start = rowptr[b];
    int deg = counts[b];
    int end = start + deg;

    for (int it = 0; it < deg; it += 64) {
        int wbase = start + it + wv * 16;
        if (wbase < end) {
            // A fragment: row = edge (wbase + c), cols 4g..4g+3, gathered by eidx
            int ar = wbase + c;
            if (ar >= end) ar = end - 1;
            uint2 reca = rec[ar];
            const float* ap = ea + (size_t)reca.y * D + 4 * g;
            f16x4 afrag = { (_Float16)__builtin_nontemporal_load(ap + 0),
                            (_Float16)__builtin_nontemporal_load(ap + 1),
                            (_Float16)__builtin_nontemporal_load(ap + 2),
                            (_Float16)__builtin_nontemporal_load(ap + 3) };
            f32x4 e4 = __builtin_amdgcn_mfma_f32_16x16x16f16(afrag, bfrag,
                          (f32x4){0.f, 0.f, 0.f, 0.f}, 0, 0, 0);
#pragma unroll
            for (int r = 0; r < 4; r++) {
                int pos = wbase + 4 * g + r;
                bool ok = pos < end;
                uint2 rc = rec[ok ? pos : end - 1];
                int src = (int)(rc.x & 0x7FFFFu);
                int tlo = (int)(rc.x >> 19);
                float qq = __half2float(qv_h[(size_t)src * 32 + c]);
                float vv = __half2float(qv_h[(size_t)src * 32 + D + c]);
                float z = kls[tlo * D + c] + e4[r] + qq;
                if (ok) {
                    float msg = vv / (1.f + __expf(-z));
                    atomicAdd(&hagg[tlo * D + c], msg);
                }
            }
        }
    }
    __syncthreads();

    // write h = hagg + skip, fused BN partial sums
    float s = 0.f, ss = 0.f;
#pragma unroll
    for (int p = 0; p < 8; ++p) {
        int nlo = seg + 16 * p;
        int node = base_node + nlo;
        if (node < n_nodes) {
            float hv = hagg[nlo * D + c] + sls[nlo * D + c];
            h[(size_t)node * D + c] = hv;
            s += hv; ss = fmaf(hv, hv, ss);
        }
    }
    s += __shfl_xor(s, 16); s += __shfl_xor(s, 32);
    ss += __shfl_xor(ss, 16); ss += __shfl_xor(ss, 32);
    if (lane < D) { red[0][wv * D + lane] = s; red[1][wv * D + lane] = ss; }
    __syncthreads();
    if (t < D) {
        float ts = 0.f, tss = 0.f;
#pragma unroll
        for (int w = 0; w < 4; w++) { ts += red[0][w * D + t]; tss += red[1][w * D + t]; }
        atomicAdd(&stats[t], ts);
        atomicAdd(&stats[D + t], tss);
    }
}

// ---------------- normalize + ReLU + residual (h lives in d_out, f32) ----------------
__global__ void bn_finalize(const float* __restrict__ x, const float* __restrict__ stats,
                            const float* __restrict__ gamma, const float* __restrict__ beta,
                            float* __restrict__ out, int n_nodes) {
    __shared__ float sc[D], sh[D];
    if (threadIdx.x < D) {
        float inv_n = 1.f / (float)n_nodes;
        float mean = stats[threadIdx.x] * inv_n;
        float var = stats[D + threadIdx.x] * inv_n - mean * mean;
        float inv = rsqrtf(var + 1e-5f);
        float g = gamma[threadIdx.x] * inv;
        sc[threadIdx.x] = g;
        sh[threadIdx.x] = beta[threadIdx.x] - mean * g;
    }
    __syncthreads();
    size_t i = (size_t)blockIdx.x * blockDim.x + threadIdx.x;
    size_t total = (size_t)n_nodes * D;
    if (i >= total) return;
    int c = (int)(i & (D - 1));
    float t = fmaf(out[i], sc[c], sh[c]);
    out[i] = x[i] + fmaxf(t, 0.f);
}

extern "C" void kernel_launch(void* const* d_in, const int* in_sizes, int n_in,
                              void* d_out, int out_size, void* d_ws, size_t ws_size,
                              hipStream_t stream) {
    const float* x     = (const float*)d_in[0];
    const int*   ei    = (const int*)d_in[1];
    const float* ea    = (const float*)d_in[2];
    const float* Wk    = (const float*)d_in[3];
    const float* bk    = (const float*)d_in[4];
    const float* Wq    = (const float*)d_in[5];
    const float* bq    = (const float*)d_in[6];
    const float* Wv    = (const float*)d_in[7];
    const float* bv    = (const float*)d_in[8];
    const float* We    = (const float*)d_in[9];
    const float* Ws    = (const float*)d_in[10];
    const float* bs    = (const float*)d_in[11];
    const float* bias  = (const float*)d_in[12];
    const float* gamma = (const float*)d_in[13];
    const float* beta  = (const float*)d_in[14];

    int n_nodes = in_sizes[0] / D;
    int n_edges = in_sizes[1] / 2;
    int nb = (n_nodes + RNODES - 1) / RNODES;   // 3907 buckets
    float* out = (float*)d_out;

    // Workspace (~72.1 MB): qv 32MB | rec 40MB | counts/rowptr/cursor/bsum | stats
    __half* qv_h  = (__half*)d_ws;                          // n*32 f16
    uint2*  rec   = (uint2*)(qv_h + (size_t)n_nodes * 32);  // n_edges * 8B
    int*    counts = (int*)(rec + n_edges);                 // nb
    int*    rowptr = counts + nb;                           // nb
    int*    cursor = rowptr + nb;                           // nb
    int*    bsum   = cursor + nb;                           // 1024
    float*  stats  = (float*)(bsum + 1024);                 // 32

    hipMemsetAsync(counts, 0, (size_t)nb * sizeof(int), stream);
    hipMemsetAsync(stats, 0, 2 * D * sizeof(float), stream);

    int nb_nodes = (n_nodes + 255) / 256;
    int nb_edges = (n_edges + 255) / 256;
    int nb_scan = (nb + SCAN_B - 1) / SCAN_B;

    node_prep_qv<<<nb_nodes, 256, 0, stream>>>(x, Wq, bq, Wv, bv, qv_h, n_nodes);
    hist_bucket<<<512, 256, 0, stream>>>(ei, counts, n_edges, nb);
    scan1<<<nb_scan, SCAN_B, 0, stream>>>(counts, rowptr, bsum, nb);
    scan2<<<1, 1024, 0, stream>>>(bsum, nb_scan);
    scan3<<<(nb + 255) / 256, 256, 0, stream>>>(rowptr, cursor, bsum, nb);
    scatter_pack<<<nb_edges, 256, 0, stream>>>(ei, cursor, rec, n_edges);

    accum_bucket<<<nb, 256, 0, stream>>>(x, ea, rec, rowptr, counts,
                                         We, Wk, bk, Ws, bs, bias, qv_h,
                                         out, stats, n_nodes, n_edges);

    size_t total = (size_t)n_nodes * D;
    int nb_fin = (int)((total + 255) / 256);
    bn_finalize<<<nb_fin, 256, 0, stream>>>(x, stats, gamma, beta, out, n_nodes);
}

// Round 9
// 537.961 us; speedup vs baseline: 1.7423x; 1.7423x over previous
//
#include <hip/hip_runtime.h>
#include <hip/hip_bf16.h>
#include <hip/hip_fp16.h>

#define D 16

typedef _Float16 f16x4 __attribute__((ext_vector_type(4)));
typedef float f32x4 __attribute__((ext_vector_type(4)));

// Fixed-point message accumulation:
//   addend per channel = round(msg*64) + 512, clamped [0,1023]  (u16 lane)
//   hagg64[node][w] (w=0..3) accumulates channels 4w..4w+3 in 16-bit lanes of a u64
//   cnt[node] counts degree; decode: msg_sum = (lane - 512*deg) / 64
#define FXS 64.0f
#define FXB 512

// ---------------- Kernel A: per-node linears ----------------
__global__ void node_prep(const float* __restrict__ x,
                          const float* __restrict__ Wk, const float* __restrict__ bk,
                          const float* __restrict__ Wq, const float* __restrict__ bq,
                          const float* __restrict__ Wv, const float* __restrict__ bv,
                          const float* __restrict__ Ws, const float* __restrict__ bs,
                          const float* __restrict__ bias,
                          __half* __restrict__ k_h, __half* __restrict__ qv_h,
                          float* __restrict__ skip, int n_nodes) {
    __shared__ float sWk[D * D], sWq[D * D], sWv[D * D], sWs[D * D], sb[4 * D];
    for (int i = threadIdx.x; i < D * D; i += blockDim.x) {
        sWk[i] = Wk[i]; sWq[i] = Wq[i]; sWv[i] = Wv[i]; sWs[i] = Ws[i];
    }
    if (threadIdx.x < D) {
        sb[threadIdx.x]         = bk[threadIdx.x];
        sb[D + threadIdx.x]     = bq[threadIdx.x];
        sb[2 * D + threadIdx.x] = bv[threadIdx.x];
        sb[3 * D + threadIdx.x] = bs[threadIdx.x] + bias[threadIdx.x];
    }
    __syncthreads();
    int n = blockIdx.x * blockDim.x + threadIdx.x;
    if (n >= n_nodes) return;

    float xr[D];
    const float4* xp = (const float4*)(x + (size_t)n * D);
#pragma unroll
    for (int i = 0; i < 4; i++) {
        float4 t = xp[i];
        xr[4*i] = t.x; xr[4*i+1] = t.y; xr[4*i+2] = t.z; xr[4*i+3] = t.w;
    }
    float kr[D], qr[D], vr[D], hr[D];
#pragma unroll
    for (int c = 0; c < D; c++) {
        kr[c] = sb[c]; qr[c] = sb[D + c]; vr[c] = sb[2*D + c]; hr[c] = sb[3*D + c];
    }
#pragma unroll
    for (int j = 0; j < D; j++) {
        float xj = xr[j];
#pragma unroll
        for (int c = 0; c < D; c++) {
            kr[c] = fmaf(xj, sWk[j * D + c], kr[c]);
            qr[c] = fmaf(xj, sWq[j * D + c], qr[c]);
            vr[c] = fmaf(xj, sWv[j * D + c], vr[c]);
            hr[c] = fmaf(xj, sWs[j * D + c], hr[c]);
        }
    }
    __align__(16) __half2 kp[8];
#pragma unroll
    for (int i = 0; i < 8; i++) kp[i] = __floats2half2_rn(kr[2*i], kr[2*i+1]);
    float4* kd = (float4*)(k_h + (size_t)n * D);
    kd[0] = *(float4*)&kp[0];
    kd[1] = *(float4*)&kp[4];
    __align__(16) __half2 qp[16];
#pragma unroll
    for (int i = 0; i < 8; i++) qp[i]     = __floats2half2_rn(qr[2*i], qr[2*i+1]);
#pragma unroll
    for (int i = 0; i < 8; i++) qp[8 + i] = __floats2half2_rn(vr[2*i], vr[2*i+1]);
    float4* qd = (float4*)(qv_h + (size_t)n * 32);
#pragma unroll
    for (int i = 0; i < 4; i++) qd[i] = *(float4*)&qp[4*i];
    float4* sp = (float4*)(skip + (size_t)n * D);
#pragma unroll
    for (int i = 0; i < 4; i++)
        sp[i] = make_float4(hr[4*i], hr[4*i+1], hr[4*i+2], hr[4*i+3]);
}

// ---------------- Kernel B: MFMA edge kernel, 5 atomics/edge ----------------
// One wave = 16 edges; MFMA computes E = EA(16x16) @ We(16x16).
// Lane l owns channel c=l&15 of edges wbase + 4*(l>>4) + r (r=reg 0..3).
__global__ void edge_msg_mfma(const int* __restrict__ ei, const float* __restrict__ ea,
                              const float* __restrict__ We,
                              const __half* __restrict__ k_h,
                              const __half* __restrict__ qv_h,
                              unsigned long long* __restrict__ hagg64,
                              unsigned* __restrict__ cnt,
                              int n_edges) {
    __shared__ __align__(16) int ssrc[64];
    __shared__ __align__(16) int stgt[64];
    int lane = threadIdx.x & 63;
    int wv = threadIdx.x >> 6;
    int c = lane & 15;
    int g = lane >> 4;

    f16x4 bfrag;
#pragma unroll
    for (int i = 0; i < 4; i++) bfrag[i] = (_Float16)We[(4*g + i) * D + c];

    long long blockbase = (long long)blockIdx.x * 64;
    {
        int t = threadIdx.x;
        if (t < 64) {
            long long e = blockbase + t;
            ssrc[t] = (e < n_edges) ? __builtin_nontemporal_load(&ei[e]) : 0;
        } else if (t < 128) {
            long long e = blockbase + (t - 64);
            stgt[t - 64] = (e < n_edges) ? __builtin_nontemporal_load(&ei[(size_t)n_edges + e]) : 0;
        }
    }
    __syncthreads();

    long long wbase = blockbase + (long long)wv * 16;
    if (wbase >= n_edges) return;

    long long arow = wbase + c;
    if (arow >= n_edges) arow = n_edges - 1;
    const float* ap = ea + (size_t)arow * D + 4 * g;
    float av0 = __builtin_nontemporal_load(ap + 0);
    float av1 = __builtin_nontemporal_load(ap + 1);
    float av2 = __builtin_nontemporal_load(ap + 2);
    float av3 = __builtin_nontemporal_load(ap + 3);
    f16x4 afrag = { (_Float16)av0, (_Float16)av1, (_Float16)av2, (_Float16)av3 };

    f32x4 e4 = __builtin_amdgcn_mfma_f32_16x16x16f16(afrag, bfrag, (f32x4){0.f,0.f,0.f,0.f}, 0, 0, 0);

    int le = wv * 16 + 4 * g;
    int4 src4 = *(const int4*)(ssrc + le);
    int4 tgt4 = *(const int4*)(stgt + le);
    int srcs[4] = { src4.x, src4.y, src4.z, src4.w };
    int tgts[4] = { tgt4.x, tgt4.y, tgt4.z, tgt4.w };

#pragma unroll
    for (int r = 0; r < 4; r++) {
        float kk = __half2float(k_h[(size_t)tgts[r] * D + c]);
        float qq = __half2float(qv_h[(size_t)srcs[r] * 32 + c]);
        float vv = __half2float(qv_h[(size_t)srcs[r] * 32 + D + c]);
        float z = kk + e4[r] + qq;
        float msg = vv / (1.f + __expf(-z));

        // biased fixed-point lane: [0, 1023]
        int a = (int)rintf(msg * FXS) + FXB;
        a = a < 0 ? 0 : (a > 1023 ? 1023 : a);
        unsigned au = (unsigned)a;

        unsigned v01 = au | ((unsigned)__shfl_xor((int)au, 1) << 16);
        unsigned v23 = (unsigned)__shfl_xor((int)v01, 2);
        unsigned long long w = (unsigned long long)v01 | ((unsigned long long)v23 << 32);

        bool ok = (wbase + 4 * g + r) < n_edges;
        if (ok && (c & 3) == 0)
            atomicAdd(&hagg64[(size_t)tgts[r] * 4 + (c >> 2)], w);
        if (ok && c == 0)
            atomicAdd(&cnt[tgts[r]], 1u);
    }
}

// ---------------- decode helper ----------------
__device__ __forceinline__ float decode_msg(const unsigned long long* hagg64,
                                            const unsigned* cnt, size_t node, int c) {
    unsigned long long w = hagg64[node * 4 + (c >> 2)];
    unsigned lane16 = (unsigned)(w >> (16 * (c & 3))) & 0xFFFFu;
    float deg = (float)cnt[node];
    return ((float)lane16 - (float)FXB * deg) * (1.0f / FXS);
}

// ---------------- Kernel C: BN statistics ----------------
__global__ void bn_stats(const float* __restrict__ skip,
                         const unsigned long long* __restrict__ hagg64,
                         const unsigned* __restrict__ cnt,
                         float* __restrict__ stats, int n_nodes) {
    float s = 0.f, ss = 0.f;
    size_t total = (size_t)n_nodes * D;
    size_t stride = (size_t)gridDim.x * blockDim.x;
    for (size_t i = (size_t)blockIdx.x * blockDim.x + threadIdx.x; i < total; i += stride) {
        float val = skip[i] + decode_msg(hagg64, cnt, i >> 4, (int)(i & 15));
        s += val;
        ss = fmaf(val, val, ss);
    }
    s += __shfl_xor(s, 16); s += __shfl_xor(s, 32);
    ss += __shfl_xor(ss, 16); ss += __shfl_xor(ss, 32);
    __shared__ float ls[4 * D], lss[4 * D];
    int wave = threadIdx.x >> 6, lane = threadIdx.x & 63;
    if (lane < D) { ls[wave * D + lane] = s; lss[wave * D + lane] = ss; }
    __syncthreads();
    if (threadIdx.x < D) {
        float ts = 0.f, tss = 0.f;
#pragma unroll
        for (int w = 0; w < 4; w++) { ts += ls[w * D + threadIdx.x]; tss += lss[w * D + threadIdx.x]; }
        atomicAdd(&stats[threadIdx.x], ts);
        atomicAdd(&stats[D + threadIdx.x], tss);
    }
}

// ---------------- Kernel D: normalize + ReLU + residual ----------------
__global__ void bn_finalize(const float* __restrict__ x,
                            const unsigned long long* __restrict__ hagg64,
                            const unsigned* __restrict__ cnt,
                            const float* __restrict__ stats,
                            const float* __restrict__ gamma, const float* __restrict__ beta,
                            float* __restrict__ out, int n_nodes) {
    __shared__ float sc[D], sh[D];
    if (threadIdx.x < D) {
        float inv_n = 1.f / (float)n_nodes;
        float mean = stats[threadIdx.x] * inv_n;
        float var = stats[D + threadIdx.x] * inv_n - mean * mean;
        float inv = rsqrtf(var + 1e-5f);
        float g = gamma[threadIdx.x] * inv;
        sc[threadIdx.x] = g;
        sh[threadIdx.x] = beta[threadIdx.x] - mean * g;
    }
    __syncthreads();
    size_t i = (size_t)blockIdx.x * blockDim.x + threadIdx.x;
    size_t total = (size_t)n_nodes * D;
    if (i >= total) return;
    int c = (int)(i & 15);
    float h = out[i] + decode_msg(hagg64, cnt, i >> 4, c);
    float t = fmaf(h, sc[c], sh[c]);
    out[i] = x[i] + fmaxf(t, 0.f);
}

extern "C" void kernel_launch(void* const* d_in, const int* in_sizes, int n_in,
                              void* d_out, int out_size, void* d_ws, size_t ws_size,
                              hipStream_t stream) {
    const float* x     = (const float*)d_in[0];
    const int*   ei    = (const int*)d_in[1];
    const float* ea    = (const float*)d_in[2];
    const float* Wk    = (const float*)d_in[3];
    const float* bk    = (const float*)d_in[4];
    const float* Wq    = (const float*)d_in[5];
    const float* bq    = (const float*)d_in[6];
    const float* Wv    = (const float*)d_in[7];
    const float* bv    = (const float*)d_in[8];
    const float* We    = (const float*)d_in[9];
    const float* Ws    = (const float*)d_in[10];
    const float* bs    = (const float*)d_in[11];
    const float* bias  = (const float*)d_in[12];
    const float* gamma = (const float*)d_in[13];
    const float* beta  = (const float*)d_in[14];

    int n_nodes = in_sizes[0] / D;
    int n_edges = in_sizes[1] / 2;
    float* out = (float*)d_out;

    // Workspace: qv 32MB | k 16MB | hagg64 16MB | cnt 2MB | stats
    __half* qv_h = (__half*)d_ws;                                   // n*32 f16
    __half* k_h  = qv_h + (size_t)n_nodes * 32;                     // n*16 f16
    unsigned long long* hagg64 = (unsigned long long*)(k_h + (size_t)n_nodes * D);  // n*4 u64
    unsigned* cnt = (unsigned*)(hagg64 + (size_t)n_nodes * 4);      // n u32
    float* stats = (float*)(cnt + n_nodes);                          // 32

    hipMemsetAsync(hagg64, 0, (size_t)n_nodes * 4 * sizeof(unsigned long long), stream);
    hipMemsetAsync(cnt, 0, (size_t)n_nodes * sizeof(unsigned), stream);
    hipMemsetAsync(stats, 0, 2 * D * sizeof(float), stream);

    int nb_nodes = (n_nodes + 255) / 256;
    node_prep<<<nb_nodes, 256, 0, stream>>>(x, Wk, bk, Wq, bq, Wv, bv, Ws, bs, bias,
                                            k_h, qv_h, out, n_nodes);

    int nb_edges = (n_edges + 63) / 64;
    edge_msg_mfma<<<nb_edges, 256, 0, stream>>>(ei, ea, We, k_h, qv_h, hagg64, cnt, n_edges);

    bn_stats<<<2048, 256, 0, stream>>>(out, hagg64, cnt, stats, n_nodes);

    size_t total = (size_t)n_nodes * D;
    int nb_fin = (int)((total + 255) / 256);
    bn_finalize<<<nb_fin, 256, 0, stream>>>(x, hagg64, cnt, stats, gamma, beta, out, n_nodes);
}

// Round 10
// 368.555 us; speedup vs baseline: 2.5431x; 1.4596x over previous
//
#include <hip/hip_runtime.h>
#include <hip/hip_bf16.h>
#include <hip/hip_fp16.h>

#define D 16

typedef _Float16 f16x4 __attribute__((ext_vector_type(4)));
typedef float f32x4 __attribute__((ext_vector_type(4)));

// ---------------- Kernel A: per-node linears ----------------
__global__ void node_prep(const float* __restrict__ x,
                          const float* __restrict__ Wk, const float* __restrict__ bk,
                          const float* __restrict__ Wq, const float* __restrict__ bq,
                          const float* __restrict__ Wv, const float* __restrict__ bv,
                          const float* __restrict__ Ws, const float* __restrict__ bs,
                          const float* __restrict__ bias,
                          __half* __restrict__ k_h, __half* __restrict__ qv_h,
                          float* __restrict__ skip, int n_nodes) {
    __shared__ float sWk[D * D], sWq[D * D], sWv[D * D], sWs[D * D], sb[4 * D];
    for (int i = threadIdx.x; i < D * D; i += blockDim.x) {
        sWk[i] = Wk[i]; sWq[i] = Wq[i]; sWv[i] = Wv[i]; sWs[i] = Ws[i];
    }
    if (threadIdx.x < D) {
        sb[threadIdx.x]         = bk[threadIdx.x];
        sb[D + threadIdx.x]     = bq[threadIdx.x];
        sb[2 * D + threadIdx.x] = bv[threadIdx.x];
        sb[3 * D + threadIdx.x] = bs[threadIdx.x] + bias[threadIdx.x];
    }
    __syncthreads();
    int n = blockIdx.x * blockDim.x + threadIdx.x;
    if (n >= n_nodes) return;

    float xr[D];
    const float4* xp = (const float4*)(x + (size_t)n * D);
#pragma unroll
    for (int i = 0; i < 4; i++) {
        float4 t = xp[i];
        xr[4*i] = t.x; xr[4*i+1] = t.y; xr[4*i+2] = t.z; xr[4*i+3] = t.w;
    }
    float kr[D], qr[D], vr[D], hr[D];
#pragma unroll
    for (int c = 0; c < D; c++) {
        kr[c] = sb[c]; qr[c] = sb[D + c]; vr[c] = sb[2*D + c]; hr[c] = sb[3*D + c];
    }
#pragma unroll
    for (int j = 0; j < D; j++) {
        float xj = xr[j];
#pragma unroll
        for (int c = 0; c < D; c++) {
            kr[c] = fmaf(xj, sWk[j * D + c], kr[c]);
            qr[c] = fmaf(xj, sWq[j * D + c], qr[c]);
            vr[c] = fmaf(xj, sWv[j * D + c], vr[c]);
            hr[c] = fmaf(xj, sWs[j * D + c], hr[c]);
        }
    }
    __align__(16) __half2 kp[8];
#pragma unroll
    for (int i = 0; i < 8; i++) kp[i] = __floats2half2_rn(kr[2*i], kr[2*i+1]);
    float4* kd = (float4*)(k_h + (size_t)n * D);
    kd[0] = *(float4*)&kp[0];
    kd[1] = *(float4*)&kp[4];
    __align__(16) __half2 qp[16];
#pragma unroll
    for (int i = 0; i < 8; i++) qp[i]     = __floats2half2_rn(qr[2*i], qr[2*i+1]);
#pragma unroll
    for (int i = 0; i < 8; i++) qp[8 + i] = __floats2half2_rn(vr[2*i], vr[2*i+1]);
    float4* qd = (float4*)(qv_h + (size_t)n * 32);
#pragma unroll
    for (int i = 0; i < 4; i++) qd[i] = *(float4*)&qp[4*i];
    float4* sp = (float4*)(skip + (size_t)n * D);
#pragma unroll
    for (int i = 0; i < 4; i++)
        sp[i] = make_float4(hr[4*i], hr[4*i+1], hr[4*i+2], hr[4*i+3]);
}

// ---------------- Kernel B: MFMA edge kernel ----------------
// One wave = 16 edges. MFMA computes E = EA(16x16) @ We(16x16).
// C layout: lane l owns channel c=l&15 of edges wbase + 4*(l>>4) + r (r=reg 0..3).
__global__ void edge_msg_mfma(const int* __restrict__ ei, const float* __restrict__ ea,
                              const float* __restrict__ We,
                              const __half* __restrict__ k_h,
                              const __half* __restrict__ qv_h,
                              __half* __restrict__ hagg,
                              int n_edges) {
    __shared__ __align__(16) int ssrc[64];
    __shared__ __align__(16) int stgt[64];
    int lane = threadIdx.x & 63;
    int wv = threadIdx.x >> 6;          // wave in block: 0..3
    int c = lane & 15;                  // channel
    int g = lane >> 4;                  // lane group: 0..3

    // B fragment: We[k][c], k = 4*g + i  (row-major We[j][c])
    f16x4 bfrag;
#pragma unroll
    for (int i = 0; i < 4; i++) bfrag[i] = (_Float16)We[(4*g + i) * D + c];

    long long blockbase = (long long)blockIdx.x * 64;
    // stage this block's 64 edges' src/tgt (coalesced, non-temporal)
    {
        int t = threadIdx.x;
        if (t < 64) {
            long long e = blockbase + t;
            ssrc[t] = (e < n_edges) ? __builtin_nontemporal_load(&ei[e]) : 0;
        } else if (t < 128) {
            long long e = blockbase + (t - 64);
            stgt[t - 64] = (e < n_edges) ? __builtin_nontemporal_load(&ei[(size_t)n_edges + e]) : 0;
        }
    }
    __syncthreads();

    long long wbase = blockbase + (long long)wv * 16;
    if (wbase >= n_edges) return;

    // A fragment: ea row = wbase + c, cols 4g..4g+3 (one float4, coalesced, NT)
    long long arow = wbase + c;
    if (arow >= n_edges) arow = n_edges - 1;
    const float* ap = ea + (size_t)arow * D + 4 * g;
    float av0 = __builtin_nontemporal_load(ap + 0);
    float av1 = __builtin_nontemporal_load(ap + 1);
    float av2 = __builtin_nontemporal_load(ap + 2);
    float av3 = __builtin_nontemporal_load(ap + 3);
    f16x4 afrag = { (_Float16)av0, (_Float16)av1, (_Float16)av2, (_Float16)av3 };

    f32x4 e4 = __builtin_amdgcn_mfma_f32_16x16x16f16(afrag, bfrag, (f32x4){0.f,0.f,0.f,0.f}, 0, 0, 0);

    int le = wv * 16 + 4 * g;           // LDS index of this lane's first owned edge
    int4 src4 = *(const int4*)(ssrc + le);
    int4 tgt4 = *(const int4*)(stgt + le);
    int srcs[4] = { src4.x, src4.y, src4.z, src4.w };
    int tgts[4] = { tgt4.x, tgt4.y, tgt4.z, tgt4.w };

    float msg[4];
#pragma unroll
    for (int r = 0; r < 4; r++) {
        float kk = __half2float(k_h[(size_t)tgts[r] * D + c]);
        float qq = __half2float(qv_h[(size_t)srcs[r] * 32 + c]);
        float vv = __half2float(qv_h[(size_t)srcs[r] * 32 + D + c]);
        float z = kk + e4[r] + qq;
        msg[r] = vv / (1.f + __expf(-z));
    }

#pragma unroll
    for (int r = 0; r < 4; r++) {
        float partner = __shfl_xor(msg[r], 1);
        long long eidx = wbase + 4 * g + r;
        if (((c & 1) == 0) && eidx < n_edges) {
            __half2 m2 = __floats2half2_rn(msg[r], partner);
            unsafeAtomicAdd((__half2*)&hagg[(size_t)tgts[r] * D + c], m2);
        }
    }
}

// ---------------- Kernel C: BN statistics ----------------
__global__ void bn_stats(const float* __restrict__ skip, const __half* __restrict__ hagg,
                         float* __restrict__ stats, int n_nodes) {
    float s = 0.f, ss = 0.f;
    size_t total = (size_t)n_nodes * D;
    size_t stride = (size_t)gridDim.x * blockDim.x;
    for (size_t i = (size_t)blockIdx.x * blockDim.x + threadIdx.x; i < total; i += stride) {
        float val = skip[i] + __half2float(hagg[i]);
        s += val;
        ss = fmaf(val, val, ss);
    }
    s += __shfl_xor(s, 16); s += __shfl_xor(s, 32);
    ss += __shfl_xor(ss, 16); ss += __shfl_xor(ss, 32);
    __shared__ float ls[4 * D], lss[4 * D];
    int wave = threadIdx.x >> 6, lane = threadIdx.x & 63;
    if (lane < D) { ls[wave * D + lane] = s; lss[wave * D + lane] = ss; }
    __syncthreads();
    if (threadIdx.x < D) {
        float ts = 0.f, tss = 0.f;
#pragma unroll
        for (int w = 0; w < 4; w++) { ts += ls[w * D + threadIdx.x]; tss += lss[w * D + threadIdx.x]; }
        atomicAdd(&stats[threadIdx.x], ts);
        atomicAdd(&stats[D + threadIdx.x], tss);
    }
}

// ---------------- Kernel D: normalize + ReLU + residual ----------------
__global__ void bn_finalize(const float* __restrict__ x, const __half* __restrict__ hagg,
                            const float* __restrict__ stats,
                            const float* __restrict__ gamma, const float* __restrict__ beta,
                            float* __restrict__ out, int n_nodes) {
    __shared__ float sc[D], sh[D];
    if (threadIdx.x < D) {
        float inv_n = 1.f / (float)n_nodes;
        float mean = stats[threadIdx.x] * inv_n;
        float var = stats[D + threadIdx.x] * inv_n - mean * mean;
        float inv = rsqrtf(var + 1e-5f);
        float g = gamma[threadIdx.x] * inv;
        sc[threadIdx.x] = g;
        sh[threadIdx.x] = beta[threadIdx.x] - mean * g;
    }
    __syncthreads();
    size_t i = (size_t)blockIdx.x * blockDim.x + threadIdx.x;
    size_t total = (size_t)n_nodes * D;
    if (i >= total) return;
    int c = (int)(i & (D - 1));
    float h = out[i] + __half2float(hagg[i]);
    float t = fmaf(h, sc[c], sh[c]);
    out[i] = x[i] + fmaxf(t, 0.f);
}

extern "C" void kernel_launch(void* const* d_in, const int* in_sizes, int n_in,
                              void* d_out, int out_size, void* d_ws, size_t ws_size,
                              hipStream_t stream) {
    const float* x     = (const float*)d_in[0];
    const int*   ei    = (const int*)d_in[1];
    const float* ea    = (const float*)d_in[2];
    const float* Wk    = (const float*)d_in[3];
    const float* bk    = (const float*)d_in[4];
    const float* Wq    = (const float*)d_in[5];
    const float* bq    = (const float*)d_in[6];
    const float* Wv    = (const float*)d_in[7];
    const float* bv    = (const float*)d_in[8];
    const float* We    = (const float*)d_in[9];
    const float* Ws    = (const float*)d_in[10];
    const float* bs    = (const float*)d_in[11];
    const float* bias  = (const float*)d_in[12];
    const float* gamma = (const float*)d_in[13];
    const float* beta  = (const float*)d_in[14];

    int n_nodes = in_sizes[0] / D;
    int n_edges = in_sizes[1] / 2;
    float* out = (float*)d_out;

    __half* qv_h = (__half*)d_ws;                       // n*32 f16 (32MB)
    __half* k_h  = qv_h + (size_t)n_nodes * 32;         // n*16 f16 (16MB)
    __half* hagg = k_h + (size_t)n_nodes * D;           // n*16 f16 (16MB)
    float* stats = (float*)(hagg + (size_t)n_nodes * D);

    hipMemsetAsync(hagg, 0, (size_t)n_nodes * D * sizeof(__half), stream);
    hipMemsetAsync(stats, 0, 2 * D * sizeof(float), stream);

    int nb_nodes = (n_nodes + 255) / 256;
    node_prep<<<nb_nodes, 256, 0, stream>>>(x, Wk, bk, Wq, bq, Wv, bv, Ws, bs, bias,
                                            k_h, qv_h, out, n_nodes);

    int nb_edges = (n_edges + 63) / 64;
    edge_msg_mfma<<<nb_edges, 256, 0, stream>>>(ei, ea, We, k_h, qv_h, hagg, n_edges);

    bn_stats<<<2048, 256, 0, stream>>>(out, hagg, stats, n_nodes);

    size_t total = (size_t)n_nodes * D;
    int nb_fin = (int)((total + 255) / 256);
    bn_finalize<<<nb_fin, 256, 0, stream>>>(x, hagg, stats, gamma, beta, out, n_nodes);
}

// Round 11
// 352.184 us; speedup vs baseline: 2.6613x; 1.0465x over previous
//
#include <hip/hip_runtime.h>
#include <hip/hip_bf16.h>
#include <hip/hip_fp16.h>

#define D 16

typedef _Float16 f16x4 __attribute__((ext_vector_type(4)));
typedef float f32x4 __attribute__((ext_vector_type(4)));

// Workspace (80MB+128B): qv[n][32]f16 | k[n][16]f16 | hagg[n][16]f16 | skip[n][16]f16 | stats[32]f32
// node_prep zeroes hagg and stats (no separate memsets); edge kernel atomics into hagg;
// bn_stats/finalize read skip+hagg as half2.

// ---------------- Kernel A: per-node linears ----------------
__global__ void node_prep(const float* __restrict__ x,
                          const float* __restrict__ Wk, const float* __restrict__ bk,
                          const float* __restrict__ Wq, const float* __restrict__ bq,
                          const float* __restrict__ Wv, const float* __restrict__ bv,
                          const float* __restrict__ Ws, const float* __restrict__ bs,
                          const float* __restrict__ bias,
                          __half* __restrict__ k_h, __half* __restrict__ qv_h,
                          __half* __restrict__ skip_h, __half* __restrict__ hagg,
                          float* __restrict__ stats, int n_nodes) {
    __shared__ float sWk[D * D], sWq[D * D], sWv[D * D], sWs[D * D], sb[4 * D];
    for (int i = threadIdx.x; i < D * D; i += blockDim.x) {
        sWk[i] = Wk[i]; sWq[i] = Wq[i]; sWv[i] = Wv[i]; sWs[i] = Ws[i];
    }
    if (threadIdx.x < D) {
        sb[threadIdx.x]         = bk[threadIdx.x];
        sb[D + threadIdx.x]     = bq[threadIdx.x];
        sb[2 * D + threadIdx.x] = bv[threadIdx.x];
        sb[3 * D + threadIdx.x] = bs[threadIdx.x] + bias[threadIdx.x];
    }
    if (blockIdx.x == 0 && threadIdx.x < 2 * D) stats[threadIdx.x] = 0.f;
    __syncthreads();
    int n = blockIdx.x * blockDim.x + threadIdx.x;
    if (n >= n_nodes) return;

    float xr[D];
    const float4* xp = (const float4*)(x + (size_t)n * D);
#pragma unroll
    for (int i = 0; i < 4; i++) {
        float4 t = xp[i];
        xr[4*i] = t.x; xr[4*i+1] = t.y; xr[4*i+2] = t.z; xr[4*i+3] = t.w;
    }
    float kr[D], qr[D], vr[D], hr[D];
#pragma unroll
    for (int c = 0; c < D; c++) {
        kr[c] = sb[c]; qr[c] = sb[D + c]; vr[c] = sb[2*D + c]; hr[c] = sb[3*D + c];
    }
#pragma unroll
    for (int j = 0; j < D; j++) {
        float xj = xr[j];
#pragma unroll
        for (int c = 0; c < D; c++) {
            kr[c] = fmaf(xj, sWk[j * D + c], kr[c]);
            qr[c] = fmaf(xj, sWq[j * D + c], qr[c]);
            vr[c] = fmaf(xj, sWv[j * D + c], vr[c]);
            hr[c] = fmaf(xj, sWs[j * D + c], hr[c]);
        }
    }
    __align__(16) __half2 kp[8];
#pragma unroll
    for (int i = 0; i < 8; i++) kp[i] = __floats2half2_rn(kr[2*i], kr[2*i+1]);
    float4* kd = (float4*)(k_h + (size_t)n * D);
    kd[0] = *(float4*)&kp[0];
    kd[1] = *(float4*)&kp[4];
    __align__(16) __half2 qp[16];
#pragma unroll
    for (int i = 0; i < 8; i++) qp[i]     = __floats2half2_rn(qr[2*i], qr[2*i+1]);
#pragma unroll
    for (int i = 0; i < 8; i++) qp[8 + i] = __floats2half2_rn(vr[2*i], vr[2*i+1]);
    float4* qd = (float4*)(qv_h + (size_t)n * 32);
#pragma unroll
    for (int i = 0; i < 4; i++) qd[i] = *(float4*)&qp[4*i];
    // skip as f16
    __align__(16) __half2 sp16[8];
#pragma unroll
    for (int i = 0; i < 8; i++) sp16[i] = __floats2half2_rn(hr[2*i], hr[2*i+1]);
    float4* sd = (float4*)(skip_h + (size_t)n * D);
    sd[0] = *(float4*)&sp16[0];
    sd[1] = *(float4*)&sp16[4];
    // zero this node's hagg row (32B)
    float4* hz = (float4*)(hagg + (size_t)n * D);
    hz[0] = make_float4(0.f, 0.f, 0.f, 0.f);
    hz[1] = make_float4(0.f, 0.f, 0.f, 0.f);
}

// ---------------- Kernel B: MFMA edge kernel (R7-proven, untouched) ----------------
__global__ void edge_msg_mfma(const int* __restrict__ ei, const float* __restrict__ ea,
                              const float* __restrict__ We,
                              const __half* __restrict__ k_h,
                              const __half* __restrict__ qv_h,
                              __half* __restrict__ hagg,
                              int n_edges) {
    __shared__ __align__(16) int ssrc[64];
    __shared__ __align__(16) int stgt[64];
    int lane = threadIdx.x & 63;
    int wv = threadIdx.x >> 6;
    int c = lane & 15;
    int g = lane >> 4;

    f16x4 bfrag;
#pragma unroll
    for (int i = 0; i < 4; i++) bfrag[i] = (_Float16)We[(4*g + i) * D + c];

    long long blockbase = (long long)blockIdx.x * 64;
    {
        int t = threadIdx.x;
        if (t < 64) {
            long long e = blockbase + t;
            ssrc[t] = (e < n_edges) ? __builtin_nontemporal_load(&ei[e]) : 0;
        } else if (t < 128) {
            long long e = blockbase + (t - 64);
            stgt[t - 64] = (e < n_edges) ? __builtin_nontemporal_load(&ei[(size_t)n_edges + e]) : 0;
        }
    }
    __syncthreads();

    long long wbase = blockbase + (long long)wv * 16;
    if (wbase >= n_edges) return;

    long long arow = wbase + c;
    if (arow >= n_edges) arow = n_edges - 1;
    const float* ap = ea + (size_t)arow * D + 4 * g;
    float av0 = __builtin_nontemporal_load(ap + 0);
    float av1 = __builtin_nontemporal_load(ap + 1);
    float av2 = __builtin_nontemporal_load(ap + 2);
    float av3 = __builtin_nontemporal_load(ap + 3);
    f16x4 afrag = { (_Float16)av0, (_Float16)av1, (_Float16)av2, (_Float16)av3 };

    f32x4 e4 = __builtin_amdgcn_mfma_f32_16x16x16f16(afrag, bfrag, (f32x4){0.f,0.f,0.f,0.f}, 0, 0, 0);

    int le = wv * 16 + 4 * g;
    int4 src4 = *(const int4*)(ssrc + le);
    int4 tgt4 = *(const int4*)(stgt + le);
    int srcs[4] = { src4.x, src4.y, src4.z, src4.w };
    int tgts[4] = { tgt4.x, tgt4.y, tgt4.z, tgt4.w };

    float msg[4];
#pragma unroll
    for (int r = 0; r < 4; r++) {
        float kk = __half2float(k_h[(size_t)tgts[r] * D + c]);
        float qq = __half2float(qv_h[(size_t)srcs[r] * 32 + c]);
        float vv = __half2float(qv_h[(size_t)srcs[r] * 32 + D + c]);
        float z = kk + e4[r] + qq;
        msg[r] = vv / (1.f + __expf(-z));
    }

#pragma unroll
    for (int r = 0; r < 4; r++) {
        float partner = __shfl_xor(msg[r], 1);
        long long eidx = wbase + 4 * g + r;
        if (((c & 1) == 0) && eidx < n_edges) {
            __half2 m2 = __floats2half2_rn(msg[r], partner);
            unsafeAtomicAdd((__half2*)&hagg[(size_t)tgts[r] * D + c], m2);
        }
    }
}

// ---------------- Kernel C: BN statistics (half2-vectorized) ----------------
__global__ void bn_stats(const __half* __restrict__ skip_h, const __half* __restrict__ hagg,
                         float* __restrict__ stats, int n_nodes) {
    float s0 = 0.f, s1 = 0.f, ss0 = 0.f, ss1 = 0.f;
    size_t total2 = (size_t)n_nodes * 8;   // half2 elements
    size_t stride = (size_t)gridDim.x * blockDim.x;  // multiple of 8
    for (size_t i = (size_t)blockIdx.x * blockDim.x + threadIdx.x; i < total2; i += stride) {
        __half2 a = ((const __half2*)skip_h)[i];
        __half2 b = ((const __half2*)hagg)[i];
        float v0 = __low2float(a) + __low2float(b);
        float v1 = __high2float(a) + __high2float(b);
        s0 += v0; ss0 = fmaf(v0, v0, ss0);
        s1 += v1; ss1 = fmaf(v1, v1, ss1);
    }
    // lanes sharing (lane&7) own the same channel pair 2a,2a+1
#pragma unroll
    for (int off = 8; off < 64; off <<= 1) {
        s0 += __shfl_xor(s0, off); s1 += __shfl_xor(s1, off);
        ss0 += __shfl_xor(ss0, off); ss1 += __shfl_xor(ss1, off);
    }
    __shared__ float ls[4 * D], lss[4 * D];
    int wave = threadIdx.x >> 6, lane = threadIdx.x & 63;
    if (lane < 8) {
        ls[wave * D + 2 * lane] = s0;  ls[wave * D + 2 * lane + 1] = s1;
        lss[wave * D + 2 * lane] = ss0; lss[wave * D + 2 * lane + 1] = ss1;
    }
    __syncthreads();
    if (threadIdx.x < D) {
        float ts = 0.f, tss = 0.f;
#pragma unroll
        for (int w = 0; w < 4; w++) { ts += ls[w * D + threadIdx.x]; tss += lss[w * D + threadIdx.x]; }
        atomicAdd(&stats[threadIdx.x], ts);
        atomicAdd(&stats[D + threadIdx.x], tss);
    }
}

// ---------------- Kernel D: normalize + ReLU + residual (half2-vectorized) ----------------
__global__ void bn_finalize(const float* __restrict__ x,
                            const __half* __restrict__ skip_h, const __half* __restrict__ hagg,
                            const float* __restrict__ stats,
                            const float* __restrict__ gamma, const float* __restrict__ beta,
                            float* __restrict__ out, int n_nodes) {
    __shared__ float sc[D], sh[D];
    if (threadIdx.x < D) {
        float inv_n = 1.f / (float)n_nodes;
        float mean = stats[threadIdx.x] * inv_n;
        float var = stats[D + threadIdx.x] * inv_n - mean * mean;
        float inv = rsqrtf(var + 1e-5f);
        float g = gamma[threadIdx.x] * inv;
        sc[threadIdx.x] = g;
        sh[threadIdx.x] = beta[threadIdx.x] - mean * g;
    }
    __syncthreads();
    size_t i = (size_t)blockIdx.x * blockDim.x + threadIdx.x;   // half2 index
    size_t total2 = (size_t)n_nodes * 8;
    if (i >= total2) return;
    int c0 = 2 * (int)(i & 7);
    __half2 a = ((const __half2*)skip_h)[i];
    __half2 b = ((const __half2*)hagg)[i];
    float2 xv = ((const float2*)x)[i];
    float h0 = __low2float(a) + __low2float(b);
    float h1 = __high2float(a) + __high2float(b);
    float t0 = fmaf(h0, sc[c0], sh[c0]);
    float t1 = fmaf(h1, sc[c0 + 1], sh[c0 + 1]);
    float2 o;
    o.x = xv.x + fmaxf(t0, 0.f);
    o.y = xv.y + fmaxf(t1, 0.f);
    ((float2*)out)[i] = o;
}

extern "C" void kernel_launch(void* const* d_in, const int* in_sizes, int n_in,
                              void* d_out, int out_size, void* d_ws, size_t ws_size,
                              hipStream_t stream) {
    const float* x     = (const float*)d_in[0];
    const int*   ei    = (const int*)d_in[1];
    const float* ea    = (const float*)d_in[2];
    const float* Wk    = (const float*)d_in[3];
    const float* bk    = (const float*)d_in[4];
    const float* Wq    = (const float*)d_in[5];
    const float* bq    = (const float*)d_in[6];
    const float* Wv    = (const float*)d_in[7];
    const float* bv    = (const float*)d_in[8];
    const float* We    = (const float*)d_in[9];
    const float* Ws    = (const float*)d_in[10];
    const float* bs    = (const float*)d_in[11];
    const float* bias  = (const float*)d_in[12];
    const float* gamma = (const float*)d_in[13];
    const float* beta  = (const float*)d_in[14];

    int n_nodes = in_sizes[0] / D;
    int n_edges = in_sizes[1] / 2;
    float* out = (float*)d_out;

    __half* qv_h   = (__half*)d_ws;                       // n*32 f16 (32MB)
    __half* k_h    = qv_h + (size_t)n_nodes * 32;         // n*16 f16 (16MB)
    __half* hagg   = k_h + (size_t)n_nodes * D;           // n*16 f16 (16MB)
    __half* skip_h = hagg + (size_t)n_nodes * D;          // n*16 f16 (16MB)
    float*  stats  = (float*)(skip_h + (size_t)n_nodes * D);

    int nb_nodes = (n_nodes + 255) / 256;
    node_prep<<<nb_nodes, 256, 0, stream>>>(x, Wk, bk, Wq, bq, Wv, bv, Ws, bs, bias,
                                            k_h, qv_h, skip_h, hagg, stats, n_nodes);

    int nb_edges = (n_edges + 63) / 64;
    edge_msg_mfma<<<nb_edges, 256, 0, stream>>>(ei, ea, We, k_h, qv_h, hagg, n_edges);

    bn_stats<<<2048, 256, 0, stream>>>(skip_h, hagg, stats, n_nodes);

    size_t total2 = (size_t)n_nodes * 8;
    int nb_fin = (int)((total2 + 255) / 256);
    bn_finalize<<<nb_fin, 256, 0, stream>>>(x, skip_h, hagg, stats, gamma, beta, out, n_nodes);
}

// Round 12
// 346.887 us; speedup vs baseline: 2.7019x; 1.0153x over previous
//
#include <hip/hip_runtime.h>
#include <hip/hip_bf16.h>
#include <hip/hip_fp16.h>

#define D 16

typedef _Float16 f16x4 __attribute__((ext_vector_type(4)));
typedef float f32x4 __attribute__((ext_vector_type(4)));

// Workspace (64MB+128B): qv[n][32]f16 | k[n][16]f16 | hagg[n][16]f16 | stats[32]f32
// node_prep seeds hagg with the skip term (x@Ws+bs+bias) in f16 and zeroes stats;
// edge kernel atomically accumulates messages on top; bn_stats/finalize read hagg only.

// ---------------- Kernel A: per-node linears ----------------
__global__ void node_prep(const float* __restrict__ x,
                          const float* __restrict__ Wk, const float* __restrict__ bk,
                          const float* __restrict__ Wq, const float* __restrict__ bq,
                          const float* __restrict__ Wv, const float* __restrict__ bv,
                          const float* __restrict__ Ws, const float* __restrict__ bs,
                          const float* __restrict__ bias,
                          __half* __restrict__ k_h, __half* __restrict__ qv_h,
                          __half* __restrict__ hagg,
                          float* __restrict__ stats, int n_nodes) {
    __shared__ float sWk[D * D], sWq[D * D], sWv[D * D], sWs[D * D], sb[4 * D];
    for (int i = threadIdx.x; i < D * D; i += blockDim.x) {
        sWk[i] = Wk[i]; sWq[i] = Wq[i]; sWv[i] = Wv[i]; sWs[i] = Ws[i];
    }
    if (threadIdx.x < D) {
        sb[threadIdx.x]         = bk[threadIdx.x];
        sb[D + threadIdx.x]     = bq[threadIdx.x];
        sb[2 * D + threadIdx.x] = bv[threadIdx.x];
        sb[3 * D + threadIdx.x] = bs[threadIdx.x] + bias[threadIdx.x];
    }
    if (blockIdx.x == 0 && threadIdx.x < 2 * D) stats[threadIdx.x] = 0.f;
    __syncthreads();
    int n = blockIdx.x * blockDim.x + threadIdx.x;
    if (n >= n_nodes) return;

    float xr[D];
    const float4* xp = (const float4*)(x + (size_t)n * D);
#pragma unroll
    for (int i = 0; i < 4; i++) {
        float4 t = xp[i];
        xr[4*i] = t.x; xr[4*i+1] = t.y; xr[4*i+2] = t.z; xr[4*i+3] = t.w;
    }
    float kr[D], qr[D], vr[D], hr[D];
#pragma unroll
    for (int c = 0; c < D; c++) {
        kr[c] = sb[c]; qr[c] = sb[D + c]; vr[c] = sb[2*D + c]; hr[c] = sb[3*D + c];
    }
#pragma unroll
    for (int j = 0; j < D; j++) {
        float xj = xr[j];
#pragma unroll
        for (int c = 0; c < D; c++) {
            kr[c] = fmaf(xj, sWk[j * D + c], kr[c]);
            qr[c] = fmaf(xj, sWq[j * D + c], qr[c]);
            vr[c] = fmaf(xj, sWv[j * D + c], vr[c]);
            hr[c] = fmaf(xj, sWs[j * D + c], hr[c]);
        }
    }
    __align__(16) __half2 kp[8];
#pragma unroll
    for (int i = 0; i < 8; i++) kp[i] = __floats2half2_rn(kr[2*i], kr[2*i+1]);
    float4* kd = (float4*)(k_h + (size_t)n * D);
    kd[0] = *(float4*)&kp[0];
    kd[1] = *(float4*)&kp[4];
    __align__(16) __half2 qp[16];
#pragma unroll
    for (int i = 0; i < 8; i++) qp[i]     = __floats2half2_rn(qr[2*i], qr[2*i+1]);
#pragma unroll
    for (int i = 0; i < 8; i++) qp[8 + i] = __floats2half2_rn(vr[2*i], vr[2*i+1]);
    float4* qd = (float4*)(qv_h + (size_t)n * 32);
#pragma unroll
    for (int i = 0; i < 4; i++) qd[i] = *(float4*)&qp[4*i];
    // seed hagg with the skip term (f16)
    __align__(16) __half2 sp16[8];
#pragma unroll
    for (int i = 0; i < 8; i++) sp16[i] = __floats2half2_rn(hr[2*i], hr[2*i+1]);
    float4* hd = (float4*)(hagg + (size_t)n * D);
    hd[0] = *(float4*)&sp16[0];
    hd[1] = *(float4*)&sp16[4];
}

// ---------------- Kernel B: MFMA edge kernel (R7-proven, untouched) ----------------
__global__ void edge_msg_mfma(const int* __restrict__ ei, const float* __restrict__ ea,
                              const float* __restrict__ We,
                              const __half* __restrict__ k_h,
                              const __half* __restrict__ qv_h,
                              __half* __restrict__ hagg,
                              int n_edges) {
    __shared__ __align__(16) int ssrc[64];
    __shared__ __align__(16) int stgt[64];
    int lane = threadIdx.x & 63;
    int wv = threadIdx.x >> 6;
    int c = lane & 15;
    int g = lane >> 4;

    f16x4 bfrag;
#pragma unroll
    for (int i = 0; i < 4; i++) bfrag[i] = (_Float16)We[(4*g + i) * D + c];

    long long blockbase = (long long)blockIdx.x * 64;
    {
        int t = threadIdx.x;
        if (t < 64) {
            long long e = blockbase + t;
            ssrc[t] = (e < n_edges) ? __builtin_nontemporal_load(&ei[e]) : 0;
        } else if (t < 128) {
            long long e = blockbase + (t - 64);
            stgt[t - 64] = (e < n_edges) ? __builtin_nontemporal_load(&ei[(size_t)n_edges + e]) : 0;
        }
    }
    __syncthreads();

    long long wbase = blockbase + (long long)wv * 16;
    if (wbase >= n_edges) return;

    long long arow = wbase + c;
    if (arow >= n_edges) arow = n_edges - 1;
    const float* ap = ea + (size_t)arow * D + 4 * g;
    float av0 = __builtin_nontemporal_load(ap + 0);
    float av1 = __builtin_nontemporal_load(ap + 1);
    float av2 = __builtin_nontemporal_load(ap + 2);
    float av3 = __builtin_nontemporal_load(ap + 3);
    f16x4 afrag = { (_Float16)av0, (_Float16)av1, (_Float16)av2, (_Float16)av3 };

    f32x4 e4 = __builtin_amdgcn_mfma_f32_16x16x16f16(afrag, bfrag, (f32x4){0.f,0.f,0.f,0.f}, 0, 0, 0);

    int le = wv * 16 + 4 * g;
    int4 src4 = *(const int4*)(ssrc + le);
    int4 tgt4 = *(const int4*)(stgt + le);
    int srcs[4] = { src4.x, src4.y, src4.z, src4.w };
    int tgts[4] = { tgt4.x, tgt4.y, tgt4.z, tgt4.w };

    float msg[4];
#pragma unroll
    for (int r = 0; r < 4; r++) {
        float kk = __half2float(k_h[(size_t)tgts[r] * D + c]);
        float qq = __half2float(qv_h[(size_t)srcs[r] * 32 + c]);
        float vv = __half2float(qv_h[(size_t)srcs[r] * 32 + D + c]);
        float z = kk + e4[r] + qq;
        msg[r] = vv / (1.f + __expf(-z));
    }

#pragma unroll
    for (int r = 0; r < 4; r++) {
        float partner = __shfl_xor(msg[r], 1);
        long long eidx = wbase + 4 * g + r;
        if (((c & 1) == 0) && eidx < n_edges) {
            __half2 m2 = __floats2half2_rn(msg[r], partner);
            unsafeAtomicAdd((__half2*)&hagg[(size_t)tgts[r] * D + c], m2);
        }
    }
}

// ---------------- Kernel C: BN statistics (half2-vectorized, hagg only) ----------------
__global__ void bn_stats(const __half* __restrict__ hagg,
                         float* __restrict__ stats, int n_nodes) {
    float s0 = 0.f, s1 = 0.f, ss0 = 0.f, ss1 = 0.f;
    size_t total2 = (size_t)n_nodes * 8;   // half2 elements
    size_t stride = (size_t)gridDim.x * blockDim.x;  // multiple of 8
    for (size_t i = (size_t)blockIdx.x * blockDim.x + threadIdx.x; i < total2; i += stride) {
        __half2 b = ((const __half2*)hagg)[i];
        float v0 = __low2float(b);
        float v1 = __high2float(b);
        s0 += v0; ss0 = fmaf(v0, v0, ss0);
        s1 += v1; ss1 = fmaf(v1, v1, ss1);
    }
#pragma unroll
    for (int off = 8; off < 64; off <<= 1) {
        s0 += __shfl_xor(s0, off); s1 += __shfl_xor(s1, off);
        ss0 += __shfl_xor(ss0, off); ss1 += __shfl_xor(ss1, off);
    }
    __shared__ float ls[4 * D], lss[4 * D];
    int wave = threadIdx.x >> 6, lane = threadIdx.x & 63;
    if (lane < 8) {
        ls[wave * D + 2 * lane] = s0;  ls[wave * D + 2 * lane + 1] = s1;
        lss[wave * D + 2 * lane] = ss0; lss[wave * D + 2 * lane + 1] = ss1;
    }
    __syncthreads();
    if (threadIdx.x < D) {
        float ts = 0.f, tss = 0.f;
#pragma unroll
        for (int w = 0; w < 4; w++) { ts += ls[w * D + threadIdx.x]; tss += lss[w * D + threadIdx.x]; }
        atomicAdd(&stats[threadIdx.x], ts);
        atomicAdd(&stats[D + threadIdx.x], tss);
    }
}

// ---------------- Kernel D: normalize + ReLU + residual (half2-vectorized) ----------------
__global__ void bn_finalize(const float* __restrict__ x,
                            const __half* __restrict__ hagg,
                            const float* __restrict__ stats,
                            const float* __restrict__ gamma, const float* __restrict__ beta,
                            float* __restrict__ out, int n_nodes) {
    __shared__ float sc[D], sh[D];
    if (threadIdx.x < D) {
        float inv_n = 1.f / (float)n_nodes;
        float mean = stats[threadIdx.x] * inv_n;
        float var = stats[D + threadIdx.x] * inv_n - mean * mean;
        float inv = rsqrtf(var + 1e-5f);
        float g = gamma[threadIdx.x] * inv;
        sc[threadIdx.x] = g;
        sh[threadIdx.x] = beta[threadIdx.x] - mean * g;
    }
    __syncthreads();
    size_t i = (size_t)blockIdx.x * blockDim.x + threadIdx.x;   // half2 index
    size_t total2 = (size_t)n_nodes * 8;
    if (i >= total2) return;
    int c0 = 2 * (int)(i & 7);
    __half2 b = ((const __half2*)hagg)[i];
    float2 xv = ((const float2*)x)[i];
    float t0 = fmaf(__low2float(b),  sc[c0],     sh[c0]);
    float t1 = fmaf(__high2float(b), sc[c0 + 1], sh[c0 + 1]);
    float2 o;
    o.x = xv.x + fmaxf(t0, 0.f);
    o.y = xv.y + fmaxf(t1, 0.f);
    ((float2*)out)[i] = o;
}

extern "C" void kernel_launch(void* const* d_in, const int* in_sizes, int n_in,
                              void* d_out, int out_size, void* d_ws, size_t ws_size,
                              hipStream_t stream) {
    const float* x     = (const float*)d_in[0];
    const int*   ei    = (const int*)d_in[1];
    const float* ea    = (const float*)d_in[2];
    const float* Wk    = (const float*)d_in[3];
    const float* bk    = (const float*)d_in[4];
    const float* Wq    = (const float*)d_in[5];
    const float* bq    = (const float*)d_in[6];
    const float* Wv    = (const float*)d_in[7];
    const float* bv    = (const float*)d_in[8];
    const float* We    = (const float*)d_in[9];
    const float* Ws    = (const float*)d_in[10];
    const float* bs    = (const float*)d_in[11];
    const float* bias  = (const float*)d_in[12];
    const float* gamma = (const float*)d_in[13];
    const float* beta  = (const float*)d_in[14];

    int n_nodes = in_sizes[0] / D;
    int n_edges = in_sizes[1] / 2;
    float* out = (float*)d_out;

    __half* qv_h = (__half*)d_ws;                       // n*32 f16 (32MB)
    __half* k_h  = qv_h + (size_t)n_nodes * 32;         // n*16 f16 (16MB)
    __half* hagg = k_h + (size_t)n_nodes * D;           // n*16 f16 (16MB), seeded with skip
    float*  stats = (float*)(hagg + (size_t)n_nodes * D);

    int nb_nodes = (n_nodes + 255) / 256;
    node_prep<<<nb_nodes, 256, 0, stream>>>(x, Wk, bk, Wq, bq, Wv, bv, Ws, bs, bias,
                                            k_h, qv_h, hagg, stats, n_nodes);

    int nb_edges = (n_edges + 63) / 64;
    edge_msg_mfma<<<nb_edges, 256, 0, stream>>>(ei, ea, We, k_h, qv_h, hagg, n_edges);

    bn_stats<<<2048, 256, 0, stream>>>(hagg, stats, n_nodes);

    size_t total2 = (size_t)n_nodes * 8;
    int nb_fin = (int)((total2 + 255) / 256);
    bn_finalize<<<nb_fin, 256, 0, stream>>>(x, hagg, stats, gamma, beta, out, n_nodes);
}